// Round 7
// baseline (4897.949 us; speedup 1.0000x reference)
//
#include <hip/hip_runtime.h>
#include <hip/hip_bf16.h>

// Transformer block, B=2 T=2048 D=1024 H=16 DH=64 F=4096. fp32 in/out.
// R7: ws usage cut to 8 MB (R6's 24 MB overran ws_size -> OOB writes corrupted
// harness pristine buffers across graph replays). d_out (16 MB) doubles as
// scratch. Attention in 4 head-group passes; FFN in 4 hidden chunks.
//   ws  [0,8MB)  bf16: O (attn out) -> F (FFN accum)
//   DO  [0,6MB)  bf16: Q/K/V quarters (per pass) -> P -> Af ; DO [8,16MB): Hc
//   final LN2 reads ws, writes fp32 d_out (everything else dead).

#define Bq_ 2
#define T_ 2048
#define D_ 1024
#define H_ 16
#define DH_ 64
#define F_ 4096
#define N_ (Bq_ * T_)   // 4096 rows
#define EPS_ 1e-5f

typedef __hip_bfloat16 bf16;
typedef unsigned short u16;

__device__ __forceinline__ u16 f2b(float f) {
    bf16 h = __float2bfloat16(f);
    return *(u16*)&h;
}
__device__ __forceinline__ float b2f_bits(u16 u) {
    return __uint_as_float(((unsigned)u) << 16);
}
__device__ __forceinline__ void unpack8(uint4 raw, float* f) {
    f[0] = __uint_as_float(raw.x << 16);
    f[1] = __uint_as_float(raw.x & 0xffff0000u);
    f[2] = __uint_as_float(raw.y << 16);
    f[3] = __uint_as_float(raw.y & 0xffff0000u);
    f[4] = __uint_as_float(raw.z << 16);
    f[5] = __uint_as_float(raw.z & 0xffff0000u);
    f[6] = __uint_as_float(raw.w << 16);
    f[7] = __uint_as_float(raw.w & 0xffff0000u);
}
__device__ __forceinline__ uint4 pack8(const float* v) {
    uint4 o;
    o.x = (unsigned)f2b(v[0]) | ((unsigned)f2b(v[1]) << 16);
    o.y = (unsigned)f2b(v[2]) | ((unsigned)f2b(v[3]) << 16);
    o.z = (unsigned)f2b(v[4]) | ((unsigned)f2b(v[5]) << 16);
    o.w = (unsigned)f2b(v[6]) | ((unsigned)f2b(v[7]) << 16);
    return o;
}

// C(bf16) = A @ Bsub (+bias)(+relu)(+ACC: C += result). fp32 accumulation.
// A: AF32 ? fp32 [N_,1024] : bf16 ws [N_,1024].  K = 1024 always.
// QKV=0: B elem = B0f[(brow_off+k)*ldb + bcol_off + j]; C = C0 + row*1024 + j.
// QKV=1: quarter proj, j in [0,768): sel=j>>8 -> Wq/Wk/Wv [16,1024,64];
//   jj=j&255, h=h0+(jj>>6), e=jj&63; elem = W[(h*1024+k)*64+e];
//   C = Csel + row*256 + jj.
// Tile 128x128, BK=16, 256 threads, 8x8 per thread.
template <int AF32, int QKV, int RELU, int ACC>
__global__ __launch_bounds__(256) void gemm_kernel(
    const void* __restrict__ A,
    const float* __restrict__ B0f, const float* __restrict__ B1f, const float* __restrict__ B2f,
    u16* __restrict__ C0, u16* __restrict__ C1, u16* __restrict__ C2,
    int ldb, int brow_off, int bcol_off, int h0,
    const float* __restrict__ bias, int bias_off)
{
    __shared__ float As[16][132];
    __shared__ float Bs[16][132];
    const int tid = threadIdx.x;
    const int tx = tid & 15, ty = tid >> 4;
    const int m0 = blockIdx.x * 128;
    const int n0 = blockIdx.y * 128;
    float c[8][8] = {};

    const int arow = tid >> 1;          // 0..127
    const int acol = (tid & 1) * 8;     // 0 or 8
    const int brow = tid >> 4;          // 0..15
    const int bcol = (tid & 15) * 8;    // 0..120

    for (int k0 = 0; k0 < 1024; k0 += 16) {
        // ---- stage A tile ----
        {
            float av[8];
            const size_t off = (size_t)(n0 + arow) * 1024 + (k0 + acol);
            if constexpr (AF32) {
                const float* fp = (const float*)A + off;
                float4 u = ((const float4*)fp)[0];
                float4 w = ((const float4*)fp)[1];
                av[0]=u.x; av[1]=u.y; av[2]=u.z; av[3]=u.w;
                av[4]=w.x; av[5]=w.y; av[6]=w.z; av[7]=w.w;
            } else {
                uint4 raw = *(const uint4*)((const u16*)A + off);
                unpack8(raw, av);
            }
            #pragma unroll
            for (int i = 0; i < 8; i++) As[acol + i][arow] = av[i];
        }
        // ---- stage B tile (fp32 weights) ----
        {
            const int k = k0 + brow;
            const int j = m0 + bcol;
            const float* bp;
            if constexpr (QKV) {
                const int sel = j >> 8;
                const int jj = j & 255;
                const int h = h0 + (jj >> 6);
                const int e = jj & 63;
                const float* Wp = (sel == 0) ? B0f : ((sel == 1) ? B1f : B2f);
                bp = Wp + ((size_t)h * 1024 + k) * 64 + e;
            } else {
                bp = B0f + (size_t)(brow_off + k) * ldb + bcol_off + j;
            }
            float4 u = ((const float4*)bp)[0];
            float4 w = ((const float4*)bp)[1];
            float4* d0 = (float4*)&Bs[brow][bcol];
            d0[0] = u;
            d0[1] = w;
        }
        __syncthreads();
        #pragma unroll
        for (int kk = 0; kk < 16; kk++) {
            float a[8], b[8];
            float4 a0 = *(const float4*)&As[kk][ty * 8];
            float4 a1 = *(const float4*)&As[kk][ty * 8 + 4];
            float4 b0 = *(const float4*)&Bs[kk][tx * 8];
            float4 b1 = *(const float4*)&Bs[kk][tx * 8 + 4];
            a[0]=a0.x; a[1]=a0.y; a[2]=a0.z; a[3]=a0.w;
            a[4]=a1.x; a[5]=a1.y; a[6]=a1.z; a[7]=a1.w;
            b[0]=b0.x; b[1]=b0.y; b[2]=b0.z; b[3]=b0.w;
            b[4]=b1.x; b[5]=b1.y; b[6]=b1.z; b[7]=b1.w;
            #pragma unroll
            for (int i = 0; i < 8; i++)
                #pragma unroll
                for (int j2 = 0; j2 < 8; j2++)
                    c[i][j2] += a[i] * b[j2];
        }
        __syncthreads();
    }
    // ---- epilogue ----
    const int j = m0 + tx * 8;
    u16* dst;
    int ldc;
    if constexpr (QKV) {
        const int sel = j >> 8;
        const int jj = j & 255;
        u16* Cp = (sel == 0) ? C0 : ((sel == 1) ? C1 : C2);
        dst = Cp + jj;
        ldc = 256;
    } else {
        dst = C0 + j;
        ldc = 1024;
    }
    #pragma unroll
    for (int i = 0; i < 8; i++) {
        const int row = n0 + ty * 8 + i;
        u16* cp = dst + (size_t)row * ldc;
        float v[8];
        #pragma unroll
        for (int j2 = 0; j2 < 8; j2++) {
            v[j2] = c[i][j2];
            if (bias) v[j2] += bias[bias_off + j + j2];
            if constexpr (RELU) v[j2] = fmaxf(v[j2], 0.f);
        }
        if constexpr (ACC) {
            float old[8];
            unpack8(*(const uint4*)cp, old);
            #pragma unroll
            for (int j2 = 0; j2 < 8; j2++) v[j2] += old[j2];
        }
        *(uint4*)cp = pack8(v);
    }
}

// Causal attention for one head-group pass (4 heads h0..h0+3).
// Qq/Kq/Vq: [N_,256] bf16 quarters (col = lh*64+e). O: [N_,1024] bf16,
// block (b,lh,t) writes O cols (h0+lh)*64..+63 of row b*T+t.
__global__ __launch_bounds__(256) void attn_kernel(const u16* __restrict__ Qq,
                                                   const u16* __restrict__ Kq,
                                                   const u16* __restrict__ Vq,
                                                   u16* __restrict__ O, int h0)
{
    const int bi = blockIdx.x;
    const int t = bi & (T_ - 1);
    const int lh = (bi >> 11) & 3;
    const int b = bi >> 13;
    const int tid = threadIdx.x;
    const int bt = b * T_ + t;

    __shared__ float qs[64];
    __shared__ float lg[T_];
    __shared__ float red[4][64];
    __shared__ float wred[4], wsum[4];

    if (tid < 64) qs[tid] = b2f_bits(Qq[(size_t)bt * 256 + lh * 64 + tid]);
    __syncthreads();

    // pass 1: logits + max
    float lmax = -1e30f;
    for (int s = tid; s <= t; s += 256) {
        const uint4* k4 = (const uint4*)(Kq + (size_t)(b * T_ + s) * 256 + lh * 64);
        float dot = 0.f;
        #pragma unroll
        for (int e = 0; e < 8; e++) {
            float kv[8];
            unpack8(k4[e], kv);
            #pragma unroll
            for (int i = 0; i < 8; i++) dot += qs[e * 8 + i] * kv[i];
        }
        float l = dot * 0.125f;   // DH^-0.5
        lg[s] = l;
        lmax = fmaxf(lmax, l);
    }
    #pragma unroll
    for (int o = 32; o > 0; o >>= 1) lmax = fmaxf(lmax, __shfl_down(lmax, o, 64));
    if ((tid & 63) == 0) wred[tid >> 6] = lmax;
    __syncthreads();
    const float gmax = fmaxf(fmaxf(wred[0], wred[1]), fmaxf(wred[2], wred[3]));

    // pass 2: exp + sum
    float lsum = 0.f;
    for (int s = tid; s <= t; s += 256) {
        float p = __expf(lg[s] - gmax);
        lg[s] = p;
        lsum += p;
    }
    #pragma unroll
    for (int o = 32; o > 0; o >>= 1) lsum += __shfl_down(lsum, o, 64);
    if ((tid & 63) == 0) wsum[tid >> 6] = lsum;
    __syncthreads();
    const float inv = 1.f / (wsum[0] + wsum[1] + wsum[2] + wsum[3]);

    // pass 3: O[e] = sum_s p[s] * V[s,e]
    const int e = tid & 63;
    const int grp = tid >> 6;
    float acc = 0.f;
    for (int s = grp; s <= t; s += 4) {
        float vv = b2f_bits(Vq[(size_t)(b * T_ + s) * 256 + lh * 64 + e]);
        acc += lg[s] * vv;
    }
    red[grp][e] = acc;
    __syncthreads();
    if (tid < 64) {
        float o = (red[0][tid] + red[1][tid] + red[2][tid] + red[3][tid]) * inv;
        O[(size_t)bt * 1024 + (h0 + lh) * 64 + tid] = f2b(o);
    }
}

// LN(src bf16)*g + be + resid(fp32). WF32=1 -> fp32 dstf, else bf16 dstb
// (in-place-safe: read-before-barrier, write-after).
template <int WF32>
__global__ __launch_bounds__(256) void ln_kernel(
    const u16* __restrict__ src, const float* __restrict__ resid,
    const float* __restrict__ g, const float* __restrict__ be,
    u16* __restrict__ dstb, float* __restrict__ dstf)
{
    const int r = blockIdx.x;
    const int tid = threadIdx.x;
    uint2 raw = ((const uint2*)(src + (size_t)r * D_))[tid];   // 4 bf16
    float y[4];
    y[0] = __uint_as_float(raw.x << 16);
    y[1] = __uint_as_float(raw.x & 0xffff0000u);
    y[2] = __uint_as_float(raw.y << 16);
    y[3] = __uint_as_float(raw.y & 0xffff0000u);
    float s = y[0] + y[1] + y[2] + y[3];
    float sq = y[0]*y[0] + y[1]*y[1] + y[2]*y[2] + y[3]*y[3];
    #pragma unroll
    for (int o = 32; o > 0; o >>= 1) {
        s += __shfl_down(s, o, 64);
        sq += __shfl_down(sq, o, 64);
    }
    __shared__ float rs[4], rq[4];
    if ((tid & 63) == 0) { rs[tid >> 6] = s; rq[tid >> 6] = sq; }
    __syncthreads();
    const float S = rs[0] + rs[1] + rs[2] + rs[3];
    const float Q = rq[0] + rq[1] + rq[2] + rq[3];
    const float mu = S * (1.f / (float)D_);
    const float var = fmaxf(Q * (1.f / (float)D_) - mu * mu, 0.f);
    const float rstd = rsqrtf(var + EPS_);
    const int c = tid * 4;
    #pragma unroll
    for (int i = 0; i < 4; i++) {
        y[i] = (y[i] - mu) * rstd * g[c + i] + be[c + i]
             + resid[(size_t)r * D_ + c + i];
    }
    if constexpr (WF32) {
        float4 o = {y[0], y[1], y[2], y[3]};
        ((float4*)(dstf + (size_t)r * D_))[tid] = o;
    } else {
        uint2 o;
        o.x = (unsigned)f2b(y[0]) | ((unsigned)f2b(y[1]) << 16);
        o.y = (unsigned)f2b(y[2]) | ((unsigned)f2b(y[3]) << 16);
        ((uint2*)(dstb + (size_t)r * D_))[tid] = o;
    }
}

extern "C" void kernel_launch(void* const* d_in, const int* in_sizes, int n_in,
                              void* d_out, int out_size, void* d_ws, size_t ws_size,
                              hipStream_t stream)
{
    const float* emb = (const float*)d_in[0];
    const float* Wq  = (const float*)d_in[1];
    const float* Wk  = (const float*)d_in[2];
    const float* Wv  = (const float*)d_in[3];
    const float* Wo  = (const float*)d_in[4];
    const float* bo  = (const float*)d_in[5];
    const float* W1  = (const float*)d_in[6];
    const float* b1  = (const float*)d_in[7];
    const float* W2  = (const float*)d_in[8];
    const float* b2  = (const float*)d_in[9];
    const float* g1  = (const float*)d_in[10];
    const float* be1 = (const float*)d_in[11];
    const float* g2  = (const float*)d_in[12];
    const float* be2 = (const float*)d_in[13];

    // Scratch regions (u16 elems):
    //   ws  [0,4M)        : O (attn output)  -> F (FFN accum)     [8 MB ws]
    //   DO  [0,1M/2M/3M)  : Q/K/V quarters per pass -> P/Af [0,4M) ; Hc [4M,8M)
    u16* WS = (u16*)d_ws;                  // 4M u16 = 8 MB
    u16* DO = (u16*)d_out;                 // 8M u16 = 16 MB (d_out as scratch)
    u16* Qq = DO;                          // [N_,256]
    u16* Kq = DO + (size_t)N_ * 256;       // [N_,256]
    u16* Vq = DO + (size_t)N_ * 512;       // [N_,256]
    u16* O  = WS;                          // [N_,1024]
    u16* P  = DO;                          // [N_,1024] (quarters dead)
    u16* Af = DO;                          // in-place LN1
    u16* Hc = DO + (size_t)N_ * 1024;      // [N_,1024] chunk
    u16* F  = WS;                          // [N_,1024] (O dead)
    float* outf = (float*)d_out;

    const dim3 blk(256);

    // Phase A: 4 head-group passes: QKV quarter proj + attention
    for (int p = 0; p < 4; p++) {
        gemm_kernel<1, 1, 0, 0><<<dim3(768 / 128, N_ / 128), blk, 0, stream>>>(
            emb, Wq, Wk, Wv, Qq, Kq, Vq, 0, 0, 0, p * 4, nullptr, 0);
        attn_kernel<<<Bq_ * 4 * T_, blk, 0, stream>>>(Qq, Kq, Vq, O, p * 4);
    }
    // Phase B: P = O @ Wo + bo  (reads ws, writes DO over dead quarters)
    gemm_kernel<0, 0, 0, 0><<<dim3(D_ / 128, N_ / 128), blk, 0, stream>>>(
        O, Wo, nullptr, nullptr, P, nullptr, nullptr, D_, 0, 0, 0, bo, 0);
    //          Af = LN(P; g1, be1) + emb  (in-place)
    ln_kernel<0><<<N_, blk, 0, stream>>>(P, emb, g1, be1, Af, nullptr);
    // Phase C: FFN in 4 hidden chunks of 1024 (Hc in DO[4M,8M), F accum in ws)
    for (int cch = 0; cch < 4; cch++) {
        gemm_kernel<0, 0, 1, 0><<<dim3(D_ / 128, N_ / 128), blk, 0, stream>>>(
            Af, W1, nullptr, nullptr, Hc, nullptr, nullptr,
            F_, 0, cch * 1024, 0, b1, cch * 1024);
        if (cch == 0) {
            gemm_kernel<0, 0, 0, 0><<<dim3(D_ / 128, N_ / 128), blk, 0, stream>>>(
                Hc, W2, nullptr, nullptr, F, nullptr, nullptr,
                D_, 0, 0, 0, b2, 0);
        } else {
            gemm_kernel<0, 0, 0, 1><<<dim3(D_ / 128, N_ / 128), blk, 0, stream>>>(
                Hc, W2, nullptr, nullptr, F, nullptr, nullptr,
                D_, cch * 1024, 0, 0, nullptr, 0);
        }
    }
    // Phase D: out = fp32(LN(F; g2, be2) + emb)  (overwrites DO, all dead)
    ln_kernel<1><<<N_, blk, 0, stream>>>(F, emb, g2, be2, nullptr, outf);
}

// Round 8
// 2092.618 us; speedup vs baseline: 2.3406x; 2.3406x over previous
//
#include <hip/hip_runtime.h>
#include <hip/hip_bf16.h>

// Transformer block, B=2 T=2048 D=1024 H=16 DH=64 F=4096. fp32 in/out.
// R8: MFMA flash attention (single dispatch, Q-tile 64, S-tile 64, online
// softmax, bf16 16x16x32 MFMA for QK^T and PV; P via LDS round-trip).
// Scratch: ws 8MB = Q -> O(in-place) -> F ; d_out 16MB = K,V -> P/Af,Hc -> out.

#define Bq_ 2
#define T_ 2048
#define D_ 1024
#define H_ 16
#define DH_ 64
#define F_ 4096
#define N_ (Bq_ * T_)   // 4096 rows
#define EPS_ 1e-5f
#define KP 72           // LDS row pitch (u16 elems): 144B, 16B-aligned rows

typedef __hip_bfloat16 bf16;
typedef unsigned short u16;
typedef __attribute__((ext_vector_type(8))) short bfrag;   // 8 bf16 = 4 VGPRs
typedef __attribute__((ext_vector_type(4))) float f32x4;

__device__ __forceinline__ u16 f2b(float f) {
    bf16 h = __float2bfloat16(f);
    return *(u16*)&h;
}
__device__ __forceinline__ float b2f_bits(u16 u) {
    return __uint_as_float(((unsigned)u) << 16);
}
__device__ __forceinline__ void unpack8(uint4 raw, float* f) {
    f[0] = __uint_as_float(raw.x << 16);
    f[1] = __uint_as_float(raw.x & 0xffff0000u);
    f[2] = __uint_as_float(raw.y << 16);
    f[3] = __uint_as_float(raw.y & 0xffff0000u);
    f[4] = __uint_as_float(raw.z << 16);
    f[5] = __uint_as_float(raw.z & 0xffff0000u);
    f[6] = __uint_as_float(raw.w << 16);
    f[7] = __uint_as_float(raw.w & 0xffff0000u);
}
__device__ __forceinline__ uint4 pack8(const float* v) {
    uint4 o;
    o.x = (unsigned)f2b(v[0]) | ((unsigned)f2b(v[1]) << 16);
    o.y = (unsigned)f2b(v[2]) | ((unsigned)f2b(v[3]) << 16);
    o.z = (unsigned)f2b(v[4]) | ((unsigned)f2b(v[5]) << 16);
    o.w = (unsigned)f2b(v[6]) | ((unsigned)f2b(v[7]) << 16);
    return o;
}

// C(bf16) = A @ Bsub (+bias)(+relu)(+ACC). fp32 accumulation. K = 1024.
// A: AF32 ? fp32 [N_,1024] : bf16 [N_,1024].
// QKV=0: B elem = B0f[(brow_off+k)*ldb + bcol_off + j]; C = C0[row*1024+j].
// QKV=1: j in [0,3072): sel=j>>10 -> Wq/Wk/Wv [16,1024,64], jj=j&1023,
//   elem = W[((jj>>6)*1024+k)*64 + (jj&63)]; C = Csel[row*1024+jj].
// Tile 128x128, BK=16, 256 threads, 8x8 per thread.
template <int AF32, int QKV, int RELU, int ACC>
__global__ __launch_bounds__(256) void gemm_kernel(
    const void* __restrict__ A,
    const float* __restrict__ B0f, const float* __restrict__ B1f, const float* __restrict__ B2f,
    u16* __restrict__ C0, u16* __restrict__ C1, u16* __restrict__ C2,
    int ldb, int brow_off, int bcol_off,
    const float* __restrict__ bias, int bias_off)
{
    __shared__ float As[16][132];
    __shared__ float Bs[16][132];
    const int tid = threadIdx.x;
    const int tx = tid & 15, ty = tid >> 4;
    const int m0 = blockIdx.x * 128;
    const int n0 = blockIdx.y * 128;
    float c[8][8] = {};

    const int arow = tid >> 1;
    const int acol = (tid & 1) * 8;
    const int brow = tid >> 4;
    const int bcol = (tid & 15) * 8;

    for (int k0 = 0; k0 < 1024; k0 += 16) {
        {
            float av[8];
            const size_t off = (size_t)(n0 + arow) * 1024 + (k0 + acol);
            if constexpr (AF32) {
                const float* fp = (const float*)A + off;
                float4 u = ((const float4*)fp)[0];
                float4 w = ((const float4*)fp)[1];
                av[0]=u.x; av[1]=u.y; av[2]=u.z; av[3]=u.w;
                av[4]=w.x; av[5]=w.y; av[6]=w.z; av[7]=w.w;
            } else {
                uint4 raw = *(const uint4*)((const u16*)A + off);
                unpack8(raw, av);
            }
            #pragma unroll
            for (int i = 0; i < 8; i++) As[acol + i][arow] = av[i];
        }
        {
            const int k = k0 + brow;
            const int j = m0 + bcol;
            const float* bp;
            if constexpr (QKV) {
                const int sel = j >> 10;
                const int jj = j & 1023;
                const float* Wp = (sel == 0) ? B0f : ((sel == 1) ? B1f : B2f);
                bp = Wp + ((size_t)(jj >> 6) * 1024 + k) * 64 + (jj & 63);
            } else {
                bp = B0f + (size_t)(brow_off + k) * ldb + bcol_off + j;
            }
            float4 u = ((const float4*)bp)[0];
            float4 w = ((const float4*)bp)[1];
            float4* d0 = (float4*)&Bs[brow][bcol];
            d0[0] = u;
            d0[1] = w;
        }
        __syncthreads();
        #pragma unroll
        for (int kk = 0; kk < 16; kk++) {
            float a[8], b[8];
            float4 a0 = *(const float4*)&As[kk][ty * 8];
            float4 a1 = *(const float4*)&As[kk][ty * 8 + 4];
            float4 b0 = *(const float4*)&Bs[kk][tx * 8];
            float4 b1 = *(const float4*)&Bs[kk][tx * 8 + 4];
            a[0]=a0.x; a[1]=a0.y; a[2]=a0.z; a[3]=a0.w;
            a[4]=a1.x; a[5]=a1.y; a[6]=a1.z; a[7]=a1.w;
            b[0]=b0.x; b[1]=b0.y; b[2]=b0.z; b[3]=b0.w;
            b[4]=b1.x; b[5]=b1.y; b[6]=b1.z; b[7]=b1.w;
            #pragma unroll
            for (int i = 0; i < 8; i++)
                #pragma unroll
                for (int j2 = 0; j2 < 8; j2++)
                    c[i][j2] += a[i] * b[j2];
        }
        __syncthreads();
    }
    const int j = m0 + tx * 8;
    u16* dst;
    if constexpr (QKV) {
        const int sel = j >> 10;
        const int jj = j & 1023;
        u16* Cp = (sel == 0) ? C0 : ((sel == 1) ? C1 : C2);
        dst = Cp + jj;
    } else {
        dst = C0 + j;
    }
    #pragma unroll
    for (int i = 0; i < 8; i++) {
        const int row = n0 + ty * 8 + i;
        u16* cp = dst + (size_t)row * 1024;
        float v[8];
        #pragma unroll
        for (int j2 = 0; j2 < 8; j2++) {
            v[j2] = c[i][j2];
            if (bias) v[j2] += bias[bias_off + j + j2];
            if constexpr (RELU) v[j2] = fmaxf(v[j2], 0.f);
        }
        if constexpr (ACC) {
            float old[8];
            unpack8(*(const uint4*)cp, old);
            #pragma unroll
            for (int j2 = 0; j2 < 8; j2++) v[j2] += old[j2];
        }
        *(uint4*)cp = pack8(v);
    }
}

// Flash attention: one block per (b, h, q-tile of 64). 4 waves; wave w owns
// Q rows w*16..+15. MFMA 16x16x32 bf16. C/D layout: row=quad*4+reg,
// col=lane&15. A layout: m=lane&15, k=quad*8+j. B layout: n=lane&15,
// k=quad*8+j. O written over Q in-place (block-private rows).
__global__ __launch_bounds__(256) void fattn_kernel(
    u16* __restrict__ Q, const u16* __restrict__ Kg, const u16* __restrict__ Vg)
{
    const int bi = blockIdx.x;
    const int qt = bi & 31;          // T/64
    const int h  = (bi >> 5) & 15;
    const int b  = bi >> 9;
    const int tid = threadIdx.x;
    const int w = tid >> 6;
    const int lane = tid & 63;
    const int lo16 = lane & 15;
    const int quad = lane >> 4;

    __shared__ alignas(16) u16 Ks[64][KP];
    __shared__ alignas(16) u16 Vt[64][KP];      // Vt[e][s]
    __shared__ alignas(16) u16 Ps[4][16][KP];   // per-wave P

    const int q0 = qt * 64;
    const size_t qrow = (size_t)(b * T_ + q0 + w * 16 + lo16) * 1024 + h * 64;
    bfrag qa0 = *(const bfrag*)(Q + qrow + quad * 8);
    bfrag qa1 = *(const bfrag*)(Q + qrow + 32 + quad * 8);

    f32x4 oacc[4] = {};
    float m_r[4], l_r[4];
    #pragma unroll
    for (int r = 0; r < 4; r++) { m_r[r] = -3e38f; l_r[r] = 0.f; }

    const int sr = tid >> 2;          // staging: row 0..63
    const int ec = (tid & 3) * 16;    // staging: col group

    for (int st = 0; st <= qt; st++) {
        const int s0 = st * 64;
        // ---- stage K[s][e] and Vt[e][s] ----
        {
            const size_t grow = (size_t)(b * T_ + s0 + sr) * 1024 + h * 64 + ec;
            uint4 ka = *(const uint4*)(Kg + grow);
            uint4 kb = *(const uint4*)(Kg + grow + 8);
            *(uint4*)&Ks[sr][ec] = ka;
            *(uint4*)&Ks[sr][ec + 8] = kb;
            uint4 va = *(const uint4*)(Vg + grow);
            uint4 vb = *(const uint4*)(Vg + grow + 8);
            unsigned vv[8] = {va.x, va.y, va.z, va.w, vb.x, vb.y, vb.z, vb.w};
            #pragma unroll
            for (int k2 = 0; k2 < 8; k2++) {
                Vt[ec + 2 * k2][sr]     = (u16)(vv[k2] & 0xffff);
                Vt[ec + 2 * k2 + 1][sr] = (u16)(vv[k2] >> 16);
            }
        }
        __syncthreads();

        // ---- QK^T: S[q][s], q=rows w*16.., s=s0+nt*16+lo16 ----
        float sv[4][4];
        #pragma unroll
        for (int nt = 0; nt < 4; nt++) {
            bfrag kb0 = *(const bfrag*)&Ks[nt * 16 + lo16][quad * 8];
            bfrag kb1 = *(const bfrag*)&Ks[nt * 16 + lo16][32 + quad * 8];
            f32x4 cs = {0.f, 0.f, 0.f, 0.f};
            cs = __builtin_amdgcn_mfma_f32_16x16x32_bf16(qa0, kb0, cs, 0, 0, 0);
            cs = __builtin_amdgcn_mfma_f32_16x16x32_bf16(qa1, kb1, cs, 0, 0, 0);
            #pragma unroll
            for (int r = 0; r < 4; r++) sv[nt][r] = cs[r] * 0.125f;
        }
        if (st == qt) {   // diagonal tile: mask s > q
            #pragma unroll
            for (int nt = 0; nt < 4; nt++)
                #pragma unroll
                for (int r = 0; r < 4; r++)
                    if (nt * 16 + lo16 > w * 16 + quad * 4 + r) sv[nt][r] = -3e38f;
        }
        // ---- online softmax (row stats via 16-lane xor-shuffles) ----
        #pragma unroll
        for (int r = 0; r < 4; r++) {
            float m = fmaxf(fmaxf(sv[0][r], sv[1][r]), fmaxf(sv[2][r], sv[3][r]));
            #pragma unroll
            for (int off = 1; off < 16; off <<= 1)
                m = fmaxf(m, __shfl_xor(m, off, 64));
            float mnew = fmaxf(m_r[r], m);
            float alpha = __expf(m_r[r] - mnew);
            m_r[r] = mnew;
            float s = 0.f;
            #pragma unroll
            for (int nt = 0; nt < 4; nt++) {
                sv[nt][r] = __expf(sv[nt][r] - mnew);
                s += sv[nt][r];
            }
            #pragma unroll
            for (int off = 1; off < 16; off <<= 1)
                s += __shfl_xor(s, off, 64);
            l_r[r] = l_r[r] * alpha + s;
            #pragma unroll
            for (int et = 0; et < 4; et++) oacc[et][r] *= alpha;
        }
        // ---- P -> LDS (C layout) then read back as A-operand ----
        #pragma unroll
        for (int nt = 0; nt < 4; nt++)
            #pragma unroll
            for (int r = 0; r < 4; r++)
                Ps[w][quad * 4 + r][nt * 16 + lo16] = f2b(sv[nt][r]);
        bfrag pa0 = *(const bfrag*)&Ps[w][lo16][quad * 8];
        bfrag pa1 = *(const bfrag*)&Ps[w][lo16][32 + quad * 8];
        // ---- PV: O[q][e] += P[q][s] V[s][e] ----
        #pragma unroll
        for (int et = 0; et < 4; et++) {
            bfrag vb0 = *(const bfrag*)&Vt[et * 16 + lo16][quad * 8];
            bfrag vb1 = *(const bfrag*)&Vt[et * 16 + lo16][32 + quad * 8];
            oacc[et] = __builtin_amdgcn_mfma_f32_16x16x32_bf16(pa0, vb0, oacc[et], 0, 0, 0);
            oacc[et] = __builtin_amdgcn_mfma_f32_16x16x32_bf16(pa1, vb1, oacc[et], 0, 0, 0);
        }
        __syncthreads();
    }
    // ---- epilogue: O = acc / l, over Q in-place ----
    #pragma unroll
    for (int r = 0; r < 4; r++) {
        float rl = 1.f / l_r[r];
        const size_t orow = (size_t)(b * T_ + q0 + w * 16 + quad * 4 + r) * 1024 + h * 64;
        #pragma unroll
        for (int et = 0; et < 4; et++)
            Q[orow + et * 16 + lo16] = f2b(oacc[et][r] * rl);
    }
}

// LN(src bf16)*g + be + resid(fp32). WF32=1 -> fp32 dstf, else bf16 dstb.
template <int WF32>
__global__ __launch_bounds__(256) void ln_kernel(
    const u16* __restrict__ src, const float* __restrict__ resid,
    const float* __restrict__ g, const float* __restrict__ be,
    u16* __restrict__ dstb, float* __restrict__ dstf)
{
    const int r = blockIdx.x;
    const int tid = threadIdx.x;
    uint2 raw = ((const uint2*)(src + (size_t)r * D_))[tid];
    float y[4];
    y[0] = __uint_as_float(raw.x << 16);
    y[1] = __uint_as_float(raw.x & 0xffff0000u);
    y[2] = __uint_as_float(raw.y << 16);
    y[3] = __uint_as_float(raw.y & 0xffff0000u);
    float s = y[0] + y[1] + y[2] + y[3];
    float sq = y[0]*y[0] + y[1]*y[1] + y[2]*y[2] + y[3]*y[3];
    #pragma unroll
    for (int o = 32; o > 0; o >>= 1) {
        s += __shfl_down(s, o, 64);
        sq += __shfl_down(sq, o, 64);
    }
    __shared__ float rs[4], rq[4];
    if ((tid & 63) == 0) { rs[tid >> 6] = s; rq[tid >> 6] = sq; }
    __syncthreads();
    const float S = rs[0] + rs[1] + rs[2] + rs[3];
    const float Qm = rq[0] + rq[1] + rq[2] + rq[3];
    const float mu = S * (1.f / (float)D_);
    const float var = fmaxf(Qm * (1.f / (float)D_) - mu * mu, 0.f);
    const float rstd = rsqrtf(var + EPS_);
    const int c = tid * 4;
    #pragma unroll
    for (int i = 0; i < 4; i++) {
        y[i] = (y[i] - mu) * rstd * g[c + i] + be[c + i]
             + resid[(size_t)r * D_ + c + i];
    }
    if constexpr (WF32) {
        float4 o = {y[0], y[1], y[2], y[3]};
        ((float4*)(dstf + (size_t)r * D_))[tid] = o;
    } else {
        uint2 o;
        o.x = (unsigned)f2b(y[0]) | ((unsigned)f2b(y[1]) << 16);
        o.y = (unsigned)f2b(y[2]) | ((unsigned)f2b(y[3]) << 16);
        ((uint2*)(dstb + (size_t)r * D_))[tid] = o;
    }
}

extern "C" void kernel_launch(void* const* d_in, const int* in_sizes, int n_in,
                              void* d_out, int out_size, void* d_ws, size_t ws_size,
                              hipStream_t stream)
{
    const float* emb = (const float*)d_in[0];
    const float* Wq  = (const float*)d_in[1];
    const float* Wk  = (const float*)d_in[2];
    const float* Wv  = (const float*)d_in[3];
    const float* Wo  = (const float*)d_in[4];
    const float* bo  = (const float*)d_in[5];
    const float* W1  = (const float*)d_in[6];
    const float* b1  = (const float*)d_in[7];
    const float* W2  = (const float*)d_in[8];
    const float* b2  = (const float*)d_in[9];
    const float* g1  = (const float*)d_in[10];
    const float* be1 = (const float*)d_in[11];
    const float* g2  = (const float*)d_in[12];
    const float* be2 = (const float*)d_in[13];

    // ws 8MB: Q [N,1024] bf16 -> O (flash, in-place) -> F (FFN accum)
    // d_out 16MB: K [0,4M), V [4M,8M) -> P/Af [0,4M), Hc [4M,8M) -> fp32 out
    u16* WS = (u16*)d_ws;
    u16* DO = (u16*)d_out;
    u16* Q  = WS;
    u16* Kb = DO;
    u16* Vb = DO + (size_t)N_ * 1024;
    u16* O  = WS;
    u16* P  = DO;
    u16* Af = DO;
    u16* Hc = DO + (size_t)N_ * 1024;
    u16* F  = WS;
    float* outf = (float*)d_out;

    const dim3 blk(256);

    // 1) Q/K/V = emb @ {Wq,Wk,Wv}
    gemm_kernel<1, 1, 0, 0><<<dim3(24, 32), blk, 0, stream>>>(
        emb, Wq, Wk, Wv, Q, Kb, Vb, 0, 0, 0, nullptr, 0);
    // 2) flash attention, O over Q
    fattn_kernel<<<Bq_ * H_ * (T_ / 64), blk, 0, stream>>>(Q, Kb, Vb);
    // 3) P = O @ Wo + bo  (over dead K)
    gemm_kernel<0, 0, 0, 0><<<dim3(8, 32), blk, 0, stream>>>(
        O, Wo, nullptr, nullptr, P, nullptr, nullptr, 1024, 0, 0, bo, 0);
    // 4) Af = LN(P) + emb (in-place)
    ln_kernel<0><<<N_, blk, 0, stream>>>(P, emb, g1, be1, Af, nullptr);
    // 5-12) FFN in 4 hidden chunks of 1024
    for (int cch = 0; cch < 4; cch++) {
        gemm_kernel<0, 0, 1, 0><<<dim3(8, 32), blk, 0, stream>>>(
            Af, W1, nullptr, nullptr, Hc, nullptr, nullptr,
            4096, 0, cch * 1024, b1, cch * 1024);
        if (cch == 0) {
            gemm_kernel<0, 0, 0, 0><<<dim3(8, 32), blk, 0, stream>>>(
                Hc, W2, nullptr, nullptr, F, nullptr, nullptr,
                1024, 0, 0, b2, 0);
        } else {
            gemm_kernel<0, 0, 0, 1><<<dim3(8, 32), blk, 0, stream>>>(
                Hc, W2, nullptr, nullptr, F, nullptr, nullptr,
                1024, cch * 1024, 0, nullptr, 0);
        }
    }
    // 13) out = fp32(LN(F) + emb)
    ln_kernel<1><<<N_, blk, 0, stream>>>(F, emb, g2, be2, nullptr, outf);
}

// Round 9
// 717.135 us; speedup vs baseline: 6.8299x; 2.9180x over previous
//
#include <hip/hip_runtime.h>
#include <hip/hip_bf16.h>

// Transformer block, B=2 T=2048 D=1024 H=16 DH=64 F=4096. fp32 in/out.
// R9: bf16-MFMA GEMMs (128x128 tile, BK=32, 4 waves x 4x4 mfma_16x16x32).
// Weights fp32 [K,M] are staged->transposed->cvt'd in-LDS each K-iter.
// Flash attention unchanged from R8. Scratch unchanged (ws 8MB + d_out 16MB).

#define Bq_ 2
#define T_ 2048
#define D_ 1024
#define H_ 16
#define DH_ 64
#define F_ 4096
#define N_ (Bq_ * T_)   // 4096 rows
#define EPS_ 1e-5f
#define KP 72           // flash-attn LDS pitch

typedef __hip_bfloat16 bf16;
typedef unsigned short u16;
typedef __attribute__((ext_vector_type(8))) short bfrag;   // 8 bf16 = 4 VGPRs
typedef __attribute__((ext_vector_type(4))) float f32x4;

__device__ __forceinline__ u16 f2b(float f) {
    bf16 h = __float2bfloat16(f);
    return *(u16*)&h;
}
__device__ __forceinline__ float b2f_bits(u16 u) {
    return __uint_as_float(((unsigned)u) << 16);
}
__device__ __forceinline__ void unpack8(uint4 raw, float* f) {
    f[0] = __uint_as_float(raw.x << 16);
    f[1] = __uint_as_float(raw.x & 0xffff0000u);
    f[2] = __uint_as_float(raw.y << 16);
    f[3] = __uint_as_float(raw.y & 0xffff0000u);
    f[4] = __uint_as_float(raw.z << 16);
    f[5] = __uint_as_float(raw.z & 0xffff0000u);
    f[6] = __uint_as_float(raw.w << 16);
    f[7] = __uint_as_float(raw.w & 0xffff0000u);
}

// C(bf16 [.,1024]) = A[N_,1024] @ Bsub (+bias)(+relu)(+ACC). fp32 accum.
// A: AF32 ? fp32 : bf16. B: fp32 global.
// QKV=0: B elem = B0f[(brow_off+k)*ldb + bcol_off + m]; C = C0.
// QKV=1: m in [0,3072): sel=m>>10 -> Wq/Wk/Wv [16,1024,64], mm=m&1023,
//        elem = W[((mm>>6)*1024+k)*64 + (mm&63)]; C = Csel, col mm.
// Tile 128x128, BK=32; wave w=(wi,wj) owns 64x64 = 4x4 mfma 16x16x32 tiles.
template <int AF32, int QKV, int RELU, int ACC>
__global__ __launch_bounds__(256) void mgemm(
    const void* __restrict__ A,
    const float* __restrict__ B0f, const float* __restrict__ B1f, const float* __restrict__ B2f,
    u16* __restrict__ C0, u16* __restrict__ C1, u16* __restrict__ C2,
    int ldb, int brow_off, int bcol_off,
    const float* __restrict__ bias, int bias_off)
{
    __shared__ alignas(16) u16 As[128][32];      // A tile, row pitch 64B
    __shared__ alignas(16) u16 Bt[128][40];      // B^T bf16, row pitch 80B
    __shared__ alignas(16) float Bs32[32][132];  // B fp32 staging

    const int tid = threadIdx.x;
    const int lane = tid & 63;
    const int w = tid >> 6;
    const int lo16 = lane & 15;
    const int quad = lane >> 4;
    const int wi = w >> 1, wj = w & 1;

    const int m0 = blockIdx.x * 128;
    const int n0 = blockIdx.y * 128;

    f32x4 acc[4][4] = {};

    const int ar  = tid >> 1;            // A stage: row 0..127
    const int akh = (tid & 1) * 16;      // A stage: k-half
    const int bmq = tid & 31;            // B stage: m-quad (m = bmq*4)
    const int bkb = (tid >> 5) * 4;      // B stage: k base (4 rows)
    const int tm  = tid >> 1;            // transpose: m row
    const int tkh = (tid & 1) * 16;      // transpose: k-half

    for (int k0 = 0; k0 < 1024; k0 += 32) {
        // ---- phase 1: issue A global loads (regs) + stage B fp32 -> Bs32 ----
        uint4 a0, a1;
        if constexpr (AF32) {
            const float* ap = (const float*)A + (size_t)(n0 + ar) * 1024 + k0 + akh;
            float4 v0 = ((const float4*)ap)[0];
            float4 v1 = ((const float4*)ap)[1];
            float4 v2 = ((const float4*)ap)[2];
            float4 v3 = ((const float4*)ap)[3];
            a0.x = (unsigned)f2b(v0.x) | ((unsigned)f2b(v0.y) << 16);
            a0.y = (unsigned)f2b(v0.z) | ((unsigned)f2b(v0.w) << 16);
            a0.z = (unsigned)f2b(v1.x) | ((unsigned)f2b(v1.y) << 16);
            a0.w = (unsigned)f2b(v1.z) | ((unsigned)f2b(v1.w) << 16);
            a1.x = (unsigned)f2b(v2.x) | ((unsigned)f2b(v2.y) << 16);
            a1.y = (unsigned)f2b(v2.z) | ((unsigned)f2b(v2.w) << 16);
            a1.z = (unsigned)f2b(v3.x) | ((unsigned)f2b(v3.y) << 16);
            a1.w = (unsigned)f2b(v3.z) | ((unsigned)f2b(v3.w) << 16);
        } else {
            const u16* ap = (const u16*)A + (size_t)(n0 + ar) * 1024 + k0 + akh;
            a0 = ((const uint4*)ap)[0];
            a1 = ((const uint4*)ap)[1];
        }
        #pragma unroll
        for (int kk = 0; kk < 4; kk++) {
            const int k = bkb + kk;
            const float* bp;
            if constexpr (QKV) {
                const int m = m0 + bmq * 4;
                const int sel = m >> 10;
                const int mm = m & 1023;
                const float* Wp = (sel == 0) ? B0f : ((sel == 1) ? B1f : B2f);
                bp = Wp + ((size_t)(mm >> 6) * 1024 + k0 + k) * 64 + (mm & 63);
            } else {
                bp = B0f + (size_t)(brow_off + k0 + k) * ldb + bcol_off + m0 + bmq * 4;
            }
            *(float4*)&Bs32[k][bmq * 4] = *(const float4*)bp;
        }
        __syncthreads();
        // ---- phase 2: write As; transpose+cvt Bs32 -> Bt ----
        *(uint4*)&As[ar][akh] = a0;
        *(uint4*)&As[ar][akh + 8] = a1;
        {
            u16 t[16];
            #pragma unroll
            for (int i = 0; i < 16; i++) t[i] = f2b(Bs32[tkh + i][tm]);
            *(uint4*)&Bt[tm][tkh] = *(uint4*)&t[0];
            *(uint4*)&Bt[tm][tkh + 8] = *(uint4*)&t[8];
        }
        __syncthreads();
        // ---- phase 3: fragments + MFMA ----
        bfrag af[4], bfv[4];
        #pragma unroll
        for (int it = 0; it < 4; it++)
            af[it] = *(const bfrag*)&As[wi * 64 + it * 16 + lo16][quad * 8];
        #pragma unroll
        for (int jt = 0; jt < 4; jt++)
            bfv[jt] = *(const bfrag*)&Bt[wj * 64 + jt * 16 + lo16][quad * 8];
        #pragma unroll
        for (int it = 0; it < 4; it++)
            #pragma unroll
            for (int jt = 0; jt < 4; jt++)
                acc[it][jt] = __builtin_amdgcn_mfma_f32_16x16x32_bf16(
                    af[it], bfv[jt], acc[it][jt], 0, 0, 0);
        __syncthreads();
    }
    // ---- epilogue: C rows n0+wi*64+it*16+quad*4+r, cols m0+wj*64+jt*16+lo16 ----
    #pragma unroll
    for (int jt = 0; jt < 4; jt++) {
        const int col = m0 + wj * 64 + jt * 16 + lo16;
        u16* Cp;
        int cc;
        if constexpr (QKV) {
            const int sel = col >> 10;
            cc = col & 1023;
            Cp = (sel == 0) ? C0 : ((sel == 1) ? C1 : C2);
        } else {
            Cp = C0;
            cc = col;
        }
        const float bv = bias ? bias[bias_off + col] : 0.f;
        #pragma unroll
        for (int it = 0; it < 4; it++) {
            #pragma unroll
            for (int r = 0; r < 4; r++) {
                const int row = n0 + wi * 64 + it * 16 + quad * 4 + r;
                float v = acc[it][jt][r] + bv;
                if constexpr (RELU) v = fmaxf(v, 0.f);
                u16* cp = Cp + (size_t)row * 1024 + cc;
                if constexpr (ACC) v += b2f_bits(*cp);
                *cp = f2b(v);
            }
        }
    }
}

// Flash attention (verified R8): one block per (b,h,q-tile 64). O over Q.
__global__ __launch_bounds__(256) void fattn_kernel(
    u16* __restrict__ Q, const u16* __restrict__ Kg, const u16* __restrict__ Vg)
{
    const int bi = blockIdx.x;
    const int qt = bi & 31;
    const int h  = (bi >> 5) & 15;
    const int b  = bi >> 9;
    const int tid = threadIdx.x;
    const int w = tid >> 6;
    const int lane = tid & 63;
    const int lo16 = lane & 15;
    const int quad = lane >> 4;

    __shared__ alignas(16) u16 Ks[64][KP];
    __shared__ alignas(16) u16 Vt[64][KP];
    __shared__ alignas(16) u16 Ps[4][16][KP];

    const int q0 = qt * 64;
    const size_t qrow = (size_t)(b * T_ + q0 + w * 16 + lo16) * 1024 + h * 64;
    bfrag qa0 = *(const bfrag*)(Q + qrow + quad * 8);
    bfrag qa1 = *(const bfrag*)(Q + qrow + 32 + quad * 8);

    f32x4 oacc[4] = {};
    float m_r[4], l_r[4];
    #pragma unroll
    for (int r = 0; r < 4; r++) { m_r[r] = -3e38f; l_r[r] = 0.f; }

    const int sr = tid >> 2;
    const int ec = (tid & 3) * 16;

    for (int st = 0; st <= qt; st++) {
        const int s0 = st * 64;
        {
            const size_t grow = (size_t)(b * T_ + s0 + sr) * 1024 + h * 64 + ec;
            uint4 ka = *(const uint4*)(Kg + grow);
            uint4 kb = *(const uint4*)(Kg + grow + 8);
            *(uint4*)&Ks[sr][ec] = ka;
            *(uint4*)&Ks[sr][ec + 8] = kb;
            uint4 va = *(const uint4*)(Vg + grow);
            uint4 vb = *(const uint4*)(Vg + grow + 8);
            unsigned vv[8] = {va.x, va.y, va.z, va.w, vb.x, vb.y, vb.z, vb.w};
            #pragma unroll
            for (int k2 = 0; k2 < 8; k2++) {
                Vt[ec + 2 * k2][sr]     = (u16)(vv[k2] & 0xffff);
                Vt[ec + 2 * k2 + 1][sr] = (u16)(vv[k2] >> 16);
            }
        }
        __syncthreads();

        float sv[4][4];
        #pragma unroll
        for (int nt = 0; nt < 4; nt++) {
            bfrag kb0 = *(const bfrag*)&Ks[nt * 16 + lo16][quad * 8];
            bfrag kb1 = *(const bfrag*)&Ks[nt * 16 + lo16][32 + quad * 8];
            f32x4 cs = {0.f, 0.f, 0.f, 0.f};
            cs = __builtin_amdgcn_mfma_f32_16x16x32_bf16(qa0, kb0, cs, 0, 0, 0);
            cs = __builtin_amdgcn_mfma_f32_16x16x32_bf16(qa1, kb1, cs, 0, 0, 0);
            #pragma unroll
            for (int r = 0; r < 4; r++) sv[nt][r] = cs[r] * 0.125f;
        }
        if (st == qt) {
            #pragma unroll
            for (int nt = 0; nt < 4; nt++)
                #pragma unroll
                for (int r = 0; r < 4; r++)
                    if (nt * 16 + lo16 > w * 16 + quad * 4 + r) sv[nt][r] = -3e38f;
        }
        #pragma unroll
        for (int r = 0; r < 4; r++) {
            float m = fmaxf(fmaxf(sv[0][r], sv[1][r]), fmaxf(sv[2][r], sv[3][r]));
            #pragma unroll
            for (int off = 1; off < 16; off <<= 1)
                m = fmaxf(m, __shfl_xor(m, off, 64));
            float mnew = fmaxf(m_r[r], m);
            float alpha = __expf(m_r[r] - mnew);
            m_r[r] = mnew;
            float s = 0.f;
            #pragma unroll
            for (int nt = 0; nt < 4; nt++) {
                sv[nt][r] = __expf(sv[nt][r] - mnew);
                s += sv[nt][r];
            }
            #pragma unroll
            for (int off = 1; off < 16; off <<= 1)
                s += __shfl_xor(s, off, 64);
            l_r[r] = l_r[r] * alpha + s;
            #pragma unroll
            for (int et = 0; et < 4; et++) oacc[et][r] *= alpha;
        }
        #pragma unroll
        for (int nt = 0; nt < 4; nt++)
            #pragma unroll
            for (int r = 0; r < 4; r++)
                Ps[w][quad * 4 + r][nt * 16 + lo16] = f2b(sv[nt][r]);
        bfrag pa0 = *(const bfrag*)&Ps[w][lo16][quad * 8];
        bfrag pa1 = *(const bfrag*)&Ps[w][lo16][32 + quad * 8];
        #pragma unroll
        for (int et = 0; et < 4; et++) {
            bfrag vb0 = *(const bfrag*)&Vt[et * 16 + lo16][quad * 8];
            bfrag vb1 = *(const bfrag*)&Vt[et * 16 + lo16][32 + quad * 8];
            oacc[et] = __builtin_amdgcn_mfma_f32_16x16x32_bf16(pa0, vb0, oacc[et], 0, 0, 0);
            oacc[et] = __builtin_amdgcn_mfma_f32_16x16x32_bf16(pa1, vb1, oacc[et], 0, 0, 0);
        }
        __syncthreads();
    }
    #pragma unroll
    for (int r = 0; r < 4; r++) {
        float rl = 1.f / l_r[r];
        const size_t orow = (size_t)(b * T_ + q0 + w * 16 + quad * 4 + r) * 1024 + h * 64;
        #pragma unroll
        for (int et = 0; et < 4; et++)
            Q[orow + et * 16 + lo16] = f2b(oacc[et][r] * rl);
    }
}

// LN(src bf16)*g + be + resid(fp32). WF32=1 -> fp32 dstf, else bf16 dstb.
template <int WF32>
__global__ __launch_bounds__(256) void ln_kernel(
    const u16* __restrict__ src, const float* __restrict__ resid,
    const float* __restrict__ g, const float* __restrict__ be,
    u16* __restrict__ dstb, float* __restrict__ dstf)
{
    const int r = blockIdx.x;
    const int tid = threadIdx.x;
    uint2 raw = ((const uint2*)(src + (size_t)r * D_))[tid];
    float y[4];
    y[0] = __uint_as_float(raw.x << 16);
    y[1] = __uint_as_float(raw.x & 0xffff0000u);
    y[2] = __uint_as_float(raw.y << 16);
    y[3] = __uint_as_float(raw.y & 0xffff0000u);
    float s = y[0] + y[1] + y[2] + y[3];
    float sq = y[0]*y[0] + y[1]*y[1] + y[2]*y[2] + y[3]*y[3];
    #pragma unroll
    for (int o = 32; o > 0; o >>= 1) {
        s += __shfl_down(s, o, 64);
        sq += __shfl_down(sq, o, 64);
    }
    __shared__ float rs[4], rq[4];
    if ((tid & 63) == 0) { rs[tid >> 6] = s; rq[tid >> 6] = sq; }
    __syncthreads();
    const float S = rs[0] + rs[1] + rs[2] + rs[3];
    const float Qm = rq[0] + rq[1] + rq[2] + rq[3];
    const float mu = S * (1.f / (float)D_);
    const float var = fmaxf(Qm * (1.f / (float)D_) - mu * mu, 0.f);
    const float rstd = rsqrtf(var + EPS_);
    const int c = tid * 4;
    #pragma unroll
    for (int i = 0; i < 4; i++) {
        y[i] = (y[i] - mu) * rstd * g[c + i] + be[c + i]
             + resid[(size_t)r * D_ + c + i];
    }
    if constexpr (WF32) {
        float4 o = {y[0], y[1], y[2], y[3]};
        ((float4*)(dstf + (size_t)r * D_))[tid] = o;
    } else {
        uint2 o;
        o.x = (unsigned)f2b(y[0]) | ((unsigned)f2b(y[1]) << 16);
        o.y = (unsigned)f2b(y[2]) | ((unsigned)f2b(y[3]) << 16);
        ((uint2*)(dstb + (size_t)r * D_))[tid] = o;
    }
}

extern "C" void kernel_launch(void* const* d_in, const int* in_sizes, int n_in,
                              void* d_out, int out_size, void* d_ws, size_t ws_size,
                              hipStream_t stream)
{
    const float* emb = (const float*)d_in[0];
    const float* Wq  = (const float*)d_in[1];
    const float* Wk  = (const float*)d_in[2];
    const float* Wv  = (const float*)d_in[3];
    const float* Wo  = (const float*)d_in[4];
    const float* bo  = (const float*)d_in[5];
    const float* W1  = (const float*)d_in[6];
    const float* b1  = (const float*)d_in[7];
    const float* W2  = (const float*)d_in[8];
    const float* b2  = (const float*)d_in[9];
    const float* g1  = (const float*)d_in[10];
    const float* be1 = (const float*)d_in[11];
    const float* g2  = (const float*)d_in[12];
    const float* be2 = (const float*)d_in[13];

    // ws 8MB: Q [N,1024] bf16 -> O (flash, in-place) -> F (FFN accum)
    // d_out 16MB: K [0,4M), V [4M,8M) -> P/Af [0,4M), Hc [4M,8M) -> fp32 out
    u16* WS = (u16*)d_ws;
    u16* DO = (u16*)d_out;
    u16* Q  = WS;
    u16* Kb = DO;
    u16* Vb = DO + (size_t)N_ * 1024;
    u16* O  = WS;
    u16* P  = DO;
    u16* Af = DO;
    u16* Hc = DO + (size_t)N_ * 1024;
    u16* F  = WS;
    float* outf = (float*)d_out;

    const dim3 blk(256);

    // 1) Q/K/V = emb @ {Wq,Wk,Wv}
    mgemm<1, 1, 0, 0><<<dim3(24, 32), blk, 0, stream>>>(
        emb, Wq, Wk, Wv, Q, Kb, Vb, 0, 0, 0, nullptr, 0);
    // 2) flash attention, O over Q
    fattn_kernel<<<Bq_ * H_ * (T_ / 64), blk, 0, stream>>>(Q, Kb, Vb);
    // 3) P = O @ Wo + bo  (over dead K)
    mgemm<0, 0, 0, 0><<<dim3(8, 32), blk, 0, stream>>>(
        O, Wo, nullptr, nullptr, P, nullptr, nullptr, 1024, 0, 0, bo, 0);
    // 4) Af = LN(P) + emb (in-place)
    ln_kernel<0><<<N_, blk, 0, stream>>>(P, emb, g1, be1, Af, nullptr);
    // 5-12) FFN in 4 hidden chunks of 1024
    for (int cch = 0; cch < 4; cch++) {
        mgemm<0, 0, 1, 0><<<dim3(8, 32), blk, 0, stream>>>(
            Af, W1, nullptr, nullptr, Hc, nullptr, nullptr,
            4096, 0, cch * 1024, b1, cch * 1024);
        if (cch == 0) {
            mgemm<0, 0, 0, 0><<<dim3(8, 32), blk, 0, stream>>>(
                Hc, W2, nullptr, nullptr, F, nullptr, nullptr,
                1024, 0, 0, b2, 0);
        } else {
            mgemm<0, 0, 0, 1><<<dim3(8, 32), blk, 0, stream>>>(
                Hc, W2, nullptr, nullptr, F, nullptr, nullptr,
                1024, cch * 1024, 0, nullptr, 0);
        }
    }
    // 13) out = fp32(LN(F) + emb)
    ln_kernel<1><<<N_, blk, 0, stream>>>(F, emb, g2, be2, nullptr, outf);
}